// Round 5
// baseline (840.327 us; speedup 1.0000x reference)
//
#include <hip/hip_runtime.h>

#define N_USERS_C 100000
#define N_ITEMS_C 40000
#define NTOT_C    140000
#define DIM_C     64
#define CDIV(a, b) (((a) + (b) - 1) / (b))

// f32 -> bf16 round-to-nearest-even
__device__ __forceinline__ unsigned short f2bf(float f) {
    unsigned u = __float_as_uint(f);
    unsigned r = (u + 0x7FFFu + ((u >> 16) & 1u)) >> 16;
    return (unsigned short)r;
}

// ---------------------------------------------------------------------------
// Direct CSR build: global per-row histogram -> 3-step hierarchical scan ->
// per-edge atomic-cursor scatter. Fully parallel (no 137-block stragglers).
// row_off/col_off support building the block-diagonal cat matrix from two
// edge lists. spack entry: (col, val_bits). In-row order is arbitrary.
// ---------------------------------------------------------------------------

__global__ __launch_bounds__(256) void row_hist(
    const int* __restrict__ rows, int row_off, int* __restrict__ cnt, int nnz) {
    int i = blockIdx.x * 256 + threadIdx.x;
    if (i < nnz) atomicAdd(&cnt[rows[i] + row_off], 1);
}

// per-block (1024 elems) exclusive scan; block totals to bsum
__global__ __launch_bounds__(256) void scan_blk(
    const int* __restrict__ cnt, int* __restrict__ rowptr,
    int* __restrict__ bsum, int n) {
    __shared__ int s[256];
    const int i0 = blockIdx.x * 1024 + threadIdx.x * 4;
    int v0 = (i0 + 0 < n) ? cnt[i0 + 0] : 0;
    int v1 = (i0 + 1 < n) ? cnt[i0 + 1] : 0;
    int v2 = (i0 + 2 < n) ? cnt[i0 + 2] : 0;
    int v3 = (i0 + 3 < n) ? cnt[i0 + 3] : 0;
    int t = v0 + v1 + v2 + v3;
    s[threadIdx.x] = t;
    __syncthreads();
    #pragma unroll
    for (int off = 1; off < 256; off <<= 1) {
        int u = (threadIdx.x >= off) ? s[threadIdx.x - off] : 0;
        __syncthreads();
        s[threadIdx.x] += u;
        __syncthreads();
    }
    int ex = s[threadIdx.x] - t;
    if (i0 + 0 < n) rowptr[i0 + 0] = ex;
    if (i0 + 1 < n) rowptr[i0 + 1] = ex + v0;
    if (i0 + 2 < n) rowptr[i0 + 2] = ex + v0 + v1;
    if (i0 + 3 < n) rowptr[i0 + 3] = ex + v0 + v1 + v2;
    if (threadIdx.x == 255) bsum[blockIdx.x] = s[255];
}

// single-block exclusive scan of <=256 block sums, in place
__global__ __launch_bounds__(256) void scan_top(int* __restrict__ bsum, int nb) {
    __shared__ int s[256];
    int v = (threadIdx.x < nb) ? bsum[threadIdx.x] : 0;
    s[threadIdx.x] = v;
    __syncthreads();
    #pragma unroll
    for (int off = 1; off < 256; off <<= 1) {
        int u = (threadIdx.x >= off) ? s[threadIdx.x - off] : 0;
        __syncthreads();
        s[threadIdx.x] += u;
        __syncthreads();
    }
    if (threadIdx.x < nb) bsum[threadIdx.x] = s[threadIdx.x] - v;
}

// add block offsets; emit final rowptr (+sentinel) and cursor copy (in cnt)
__global__ __launch_bounds__(256) void scan_add(
    int* __restrict__ rowptr, const int* __restrict__ bsum,
    int* __restrict__ cursor, int n, int nnz) {
    int i = blockIdx.x * 256 + threadIdx.x;
    if (i < n) {
        int v = rowptr[i] + bsum[i >> 10];
        rowptr[i] = v;
        cursor[i] = v;
    }
    if (i == 0) rowptr[n] = nnz;
}

__global__ __launch_bounds__(256) void direct_scatter(
    const int* __restrict__ rows, const int* __restrict__ cols,
    const float* __restrict__ vals, int row_off, int col_off,
    int* __restrict__ cursor, int2* __restrict__ spack, int nnz) {
    int i = blockIdx.x * 256 + threadIdx.x;
    if (i >= nnz) return;
    int pos = atomicAdd(&cursor[rows[i] + row_off], 1);
    spack[pos] = make_int2(cols[i] + col_off, __float_as_int(vals[i]));
}

// ---------------------------------------------------------------------------
// f32 -> bf16: dst[0..n4A) <- A, dst[n4A..n4tot) <- B  (float4 granularity)
// ---------------------------------------------------------------------------
__global__ __launch_bounds__(256) void concat2_to_bf16(
    const float* __restrict__ A, const float* __restrict__ B, int n4A,
    int n4tot, unsigned short* __restrict__ dst) {
    int gid = blockIdx.x * blockDim.x + threadIdx.x;
    if (gid >= n4tot) return;
    float4 v = (gid < n4A) ? ((const float4*)A)[gid] : ((const float4*)B)[gid - n4A];
    ushort4 o;
    o.x = f2bf(v.x); o.y = f2bf(v.y); o.z = f2bf(v.z); o.w = f2bf(v.w);
    ((ushort4*)dst)[gid] = o;
}

// ---------------------------------------------------------------------------
// Gather SpMM (CSR): 4 rows per wave, 16 lanes per row, 4 dims per lane.
// 4 independent edge streams/wave, unroll-4 each, software-pipelined
// descriptor prefetch. Tail slots gather a hot line and multiply by 0.
// MODE 0: out_bf = bf16(s)
// MODE 1: out_bf = bf16(s); acc = ego0 + s                (ui layer 1)
// MODE 2: out_bf = bf16(s); acc += s                      (ui layer 2)
// MODE 3: acc += s                                        (ui layer 3)
// MODE 4: out_f32 = s; acc = acc*0.25 + s/max(||s||,eps)  (separate ii/uu final)
// MODE 5: same as 4 but block-diagonal cat row->acc row mapping
// Requires n_rows % 16 == 0 (140000/100000/40000 all qualify).
// ---------------------------------------------------------------------------
template <int MODE>
__global__ __launch_bounds__(256) void spmm_csr4(
    const int* __restrict__ rowptr, const int2* __restrict__ spack,
    const unsigned short* __restrict__ x, unsigned short* __restrict__ out_bf,
    float* __restrict__ out_f32, float* __restrict__ acc,
    const float* __restrict__ ego_u, const float* __restrict__ ego_i,
    int n_rows, int nnz) {
    const int wq   = (blockIdx.x * 256 + threadIdx.x) >> 6;  // row quad id
    const int lane = threadIdx.x & 63;
    const int l    = lane & 15;            // lane within row group
    const int row  = wq * 4 + (lane >> 4);

    int j = rowptr[row];
    int e = rowptr[row + 1];
    int rem = e - j;                              // uniform within 16-lane group
    int m1 = max(rem, __shfl_xor(rem, 16, 64));
    int mrem = max(m1, __shfl_xor(m1, 32, 64));   // uniform across wave

    const uint2* __restrict__ xq = (const uint2*)x;  // 4 bf16 per uint2
    const int last = nnz - 1;

    float4 sa[4];
    #pragma unroll
    for (int u = 0; u < 4; ++u) sa[u] = make_float4(0.f, 0.f, 0.f, 0.f);

    if (mrem > 0) {
        int base = j;
        int2 p[4];
        #pragma unroll
        for (int u = 0; u < 4; ++u) p[u] = spack[min(base + u, last)];
        for (;;) {
            uint2 g[4];
            #pragma unroll
            for (int u = 0; u < 4; ++u)
                g[u] = xq[(u < rem) ? ((p[u].x << 4) + l) : l];
            int nb = base + 4;
            int2 q[4];
            #pragma unroll
            for (int u = 0; u < 4; ++u) q[u] = spack[min(nb + u, last)];
            #pragma unroll
            for (int u = 0; u < 4; ++u) {
                float v = (u < rem) ? __int_as_float(p[u].y) : 0.f;
                sa[u].x += v * __uint_as_float(g[u].x << 16);
                sa[u].y += v * __uint_as_float(g[u].x & 0xFFFF0000u);
                sa[u].z += v * __uint_as_float(g[u].y << 16);
                sa[u].w += v * __uint_as_float(g[u].y & 0xFFFF0000u);
            }
            mrem -= 4;
            if (mrem <= 0) break;
            rem -= 4;
            base = nb;
            #pragma unroll
            for (int u = 0; u < 4; ++u) p[u] = q[u];
        }
    }
    float4 s;
    s.x = (sa[0].x + sa[1].x) + (sa[2].x + sa[3].x);
    s.y = (sa[0].y + sa[1].y) + (sa[2].y + sa[3].y);
    s.z = (sa[0].z + sa[1].z) + (sa[2].z + sa[3].z);
    s.w = (sa[0].w + sa[1].w) + (sa[2].w + sa[3].w);

    const size_t idx4 = (size_t)row * 16 + l;  // float4 / ushort4 units
    if (MODE == 0 || MODE == 1 || MODE == 2) {
        ushort4 o;
        o.x = f2bf(s.x); o.y = f2bf(s.y); o.z = f2bf(s.z); o.w = f2bf(s.w);
        ((ushort4*)out_bf)[idx4] = o;
    }
    if (MODE == 1) {
        float4 e4 = (row < N_USERS_C)
            ? ((const float4*)ego_u)[idx4]
            : ((const float4*)ego_i)[(size_t)(row - N_USERS_C) * 16 + l];
        ((float4*)acc)[idx4] = make_float4(e4.x + s.x, e4.y + s.y,
                                           e4.z + s.z, e4.w + s.w);
    } else if (MODE == 2 || MODE == 3) {
        float4 a = ((const float4*)acc)[idx4];
        ((float4*)acc)[idx4] = make_float4(a.x + s.x, a.y + s.y,
                                           a.z + s.z, a.w + s.w);
    } else if (MODE == 4 || MODE == 5) {
        ((float4*)out_f32)[idx4] = s;
        float ss = s.x * s.x + s.y * s.y + s.z * s.z + s.w * s.w;
        #pragma unroll
        for (int off = 1; off < 16; off <<= 1) ss += __shfl_xor(ss, off, 64);
        float inv = 1.f / fmaxf(sqrtf(ss), 1e-12f);
        size_t aidx = idx4;
        if (MODE == 5) {
            int arow = (row < N_ITEMS_C) ? (N_USERS_C + row) : (row - N_ITEMS_C);
            aidx = (size_t)arow * 16 + l;
        }
        float4 a = ((const float4*)acc)[aidx];
        a.x = a.x * 0.25f + s.x * inv;
        a.y = a.y * 0.25f + s.y * inv;
        a.z = a.z * 0.25f + s.z * inv;
        a.w = a.w * 0.25f + s.w * inv;
        ((float4*)acc)[aidx] = a;
    }
}

// ---------------------------------------------------------------------------

template <int MODE>
static inline void run_spmm(const int* rowptr, const int2* spack,
                            const unsigned short* x, unsigned short* out_bf,
                            float* out_f32, float* acc, const float* ego_u,
                            const float* ego_i, int n_rows, int nnz, hipStream_t s) {
    spmm_csr4<MODE><<<n_rows / 16, 256, 0, s>>>(rowptr, spack, x, out_bf, out_f32,
                                                acc, ego_u, ego_i, n_rows, nnz);
}

// scan trio: cnt -> rowptr(+sentinel) + cursor (cursor written into cnt)
static inline void build_scan(int* cnt, int* rowptr, int* bsum, int n_rows,
                              int nnz, hipStream_t s) {
    int nblk = CDIV(n_rows, 1024);  // <= 137 <= 256
    scan_blk<<<nblk, 256, 0, s>>>(cnt, rowptr, bsum, n_rows);
    scan_top<<<1, 256, 0, s>>>(bsum, nblk);
    scan_add<<<CDIV(n_rows, 256), 256, 0, s>>>(rowptr, bsum, cnt, n_rows, nnz);
}

extern "C" void kernel_launch(void* const* d_in, const int* in_sizes, int n_in,
                              void* d_out, int out_size, void* d_ws, size_t ws_size,
                              hipStream_t stream) {
    const float* user_ui = (const float*)d_in[0];
    const float* item_ui = (const float*)d_in[1];
    const float* uu_emb  = (const float*)d_in[2];
    const float* ii_emb  = (const float*)d_in[3];
    const float* ui_vals = (const float*)d_in[4];
    const float* ii_vals = (const float*)d_in[5];
    const float* uu_vals = (const float*)d_in[6];
    const int* ui_rows = (const int*)d_in[7];
    const int* ui_cols = (const int*)d_in[8];
    const int* ii_rows = (const int*)d_in[9];
    const int* ii_cols = (const int*)d_in[10];
    const int* uu_rows = (const int*)d_in[11];
    const int* uu_cols = (const int*)d_in[12];
    const int nnz_ui = in_sizes[4];
    const int nnz_ii = in_sizes[5];
    const int nnz_uu = in_sizes[6];
    const int nnz_cat = nnz_ii + nnz_uu;

    float* out    = (float*)d_out;
    float* acc    = out;                                  // [140000, 64]
    float* acc_u  = acc;
    float* acc_i  = acc + (size_t)N_USERS_C * DIM_C;
    float* out_ii = out + (size_t)NTOT_C * DIM_C;         // [40000, 64]
    float* out_uu = out_ii + (size_t)N_ITEMS_C * DIM_C;   // [100000, 64]
    float* out_cat = out_ii;  // out_ii then out_uu contiguous -> cat rows 1:1

    const size_t buf_bytes = (size_t)NTOT_C * DIM_C * sizeof(unsigned short);
    const size_t sp_ui  = (size_t)nnz_ui * sizeof(int2);
    const size_t sp_ii  = (size_t)nnz_ii * sizeof(int2);
    const size_t sp_uu  = (size_t)nnz_uu * sizeof(int2);
    const size_t sp_cat = (size_t)nnz_cat * sizeof(int2);
    const size_t meta_bytes = (size_t)(NTOT_C + 1 + 256) * sizeof(int);

    size_t slot_sep = sp_ui > sp_ii ? (sp_ui > sp_uu ? sp_ui : sp_uu)
                                    : (sp_ii > sp_uu ? sp_ii : sp_uu);
    size_t slot_cat = sp_cat > sp_ui ? sp_cat : sp_ui;
    bool use_cat = ws_size >= slot_cat + 2 * buf_bytes + meta_bytes;
    size_t slotA = use_cat ? slot_cat : slot_sep;

    // Layout: [spack][buf0 (head doubles as cnt/cursor when bufs dead)][buf1][meta]
    char* p = (char*)d_ws;
    int2* spack = (int2*)p;                     p += slotA;
    unsigned short* buf0 = (unsigned short*)p;
    int* cnt = (int*)p;                         p += buf_bytes;
    unsigned short* buf1 = (unsigned short*)p;  p += buf_bytes;
    int* rowptr = (int*)p;
    int* bsum   = rowptr + (NTOT_C + 1);

    const int n4tot = NTOT_C * DIM_C / 4;
    const int n4u   = N_USERS_C * DIM_C / 4;
    const int n4i   = N_ITEMS_C * DIM_C / 4;

    // ==== ui chain (3 layers; acc lives in d_out head) ====
    hipMemsetAsync(cnt, 0, (size_t)NTOT_C * sizeof(int), stream);
    row_hist<<<CDIV(nnz_ui, 256), 256, 0, stream>>>(ui_rows, 0, cnt, nnz_ui);
    build_scan(cnt, rowptr, bsum, NTOT_C, nnz_ui, stream);
    direct_scatter<<<CDIV(nnz_ui, 256), 256, 0, stream>>>(
        ui_rows, ui_cols, ui_vals, 0, 0, cnt, spack, nnz_ui);
    concat2_to_bf16<<<CDIV(n4tot, 256), 256, 0, stream>>>(user_ui, item_ui,
                                                          n4u, n4tot, buf1);
    run_spmm<1>(rowptr, spack, buf1, buf0, nullptr, acc, user_ui, item_ui,
                NTOT_C, nnz_ui, stream);
    run_spmm<2>(rowptr, spack, buf0, buf1, nullptr, acc, nullptr, nullptr,
                NTOT_C, nnz_ui, stream);
    run_spmm<3>(rowptr, spack, buf1, nullptr, nullptr, acc, nullptr, nullptr,
                NTOT_C, nnz_ui, stream);

    if (use_cat) {
        // ==== fused ii+uu chain: diag(S_ii, S_uu) on [ii_emb; uu_emb] ====
        hipMemsetAsync(cnt, 0, (size_t)NTOT_C * sizeof(int), stream);
        row_hist<<<CDIV(nnz_ii, 256), 256, 0, stream>>>(ii_rows, 0, cnt, nnz_ii);
        row_hist<<<CDIV(nnz_uu, 256), 256, 0, stream>>>(uu_rows, N_ITEMS_C, cnt,
                                                        nnz_uu);
        build_scan(cnt, rowptr, bsum, NTOT_C, nnz_cat, stream);
        direct_scatter<<<CDIV(nnz_ii, 256), 256, 0, stream>>>(
            ii_rows, ii_cols, ii_vals, 0, 0, cnt, spack, nnz_ii);
        direct_scatter<<<CDIV(nnz_uu, 256), 256, 0, stream>>>(
            uu_rows, uu_cols, uu_vals, N_ITEMS_C, N_ITEMS_C, cnt, spack, nnz_uu);
        concat2_to_bf16<<<CDIV(n4tot, 256), 256, 0, stream>>>(ii_emb, uu_emb,
                                                              n4i, n4tot, buf1);
        run_spmm<0>(rowptr, spack, buf1, buf0, nullptr, nullptr, nullptr, nullptr,
                    NTOT_C, nnz_cat, stream);
        run_spmm<5>(rowptr, spack, buf0, nullptr, out_cat, acc, nullptr, nullptr,
                    NTOT_C, nnz_cat, stream);
    } else {
        // ==== fallback: separate ii / uu chains, same direct build ====
        hipMemsetAsync(cnt, 0, (size_t)NTOT_C * sizeof(int), stream);
        // ii (uses cnt[0..N_ITEMS))
        row_hist<<<CDIV(nnz_ii, 256), 256, 0, stream>>>(ii_rows, 0, cnt, nnz_ii);
        build_scan(cnt, rowptr, bsum, N_ITEMS_C, nnz_ii, stream);
        direct_scatter<<<CDIV(nnz_ii, 256), 256, 0, stream>>>(
            ii_rows, ii_cols, ii_vals, 0, 0, cnt, spack, nnz_ii);
        concat2_to_bf16<<<CDIV(n4i, 256), 256, 0, stream>>>(ii_emb, ii_emb,
                                                            n4i, n4i, buf0);
        run_spmm<0>(rowptr, spack, buf0, buf1, nullptr, nullptr, nullptr, nullptr,
                    N_ITEMS_C, nnz_ii, stream);
        run_spmm<4>(rowptr, spack, buf1, nullptr, out_ii, acc_i, nullptr, nullptr,
                    N_ITEMS_C, nnz_ii, stream);
        // uu (uses cnt[N_ITEMS..NTOT), still zeroed; ii spmm done -> buf0 dead)
        int* cnt2 = cnt + N_ITEMS_C;
        row_hist<<<CDIV(nnz_uu, 256), 256, 0, stream>>>(uu_rows, 0, cnt2, nnz_uu);
        build_scan(cnt2, rowptr, bsum, N_USERS_C, nnz_uu, stream);
        direct_scatter<<<CDIV(nnz_uu, 256), 256, 0, stream>>>(
            uu_rows, uu_cols, uu_vals, 0, 0, cnt2, spack, nnz_uu);
        concat2_to_bf16<<<CDIV(n4u, 256), 256, 0, stream>>>(uu_emb, uu_emb,
                                                            n4u, n4u, buf0);
        run_spmm<0>(rowptr, spack, buf0, buf1, nullptr, nullptr, nullptr, nullptr,
                    N_USERS_C, nnz_uu, stream);
        run_spmm<4>(rowptr, spack, buf1, nullptr, out_uu, acc_u, nullptr, nullptr,
                    N_USERS_C, nnz_uu, stream);
    }
}

// Round 6
// 612.715 us; speedup vs baseline: 1.3715x; 1.3715x over previous
//
#include <hip/hip_runtime.h>

#define N_USERS_C 100000
#define N_ITEMS_C 40000
#define NTOT_C    140000
#define DIM_C     64
#define CDIV(a, b) (((a) + (b) - 1) / (b))

// f32 -> bf16 round-to-nearest-even
__device__ __forceinline__ unsigned short f2bf(float f) {
    unsigned u = __float_as_uint(f);
    unsigned r = (u + 0x7FFFu + ((u >> 16) & 1u)) >> 16;
    return (unsigned short)r;
}

// ---------------------------------------------------------------------------
// Bucketed counting-sort CSR build. Bucket = 1<<LOG_BR consecutive rows,
// NB <= 256. inter[] entry: x = (row_local << 18) | col (col < 2^18), y = val.
// row_off/col_off let two edge lists build one block-diagonal matrix.
// ---------------------------------------------------------------------------

// P0: LDS-aggregated bucket histogram. bkt_count pre-zeroed.
template <int LOG_BR>
__global__ __launch_bounds__(256) void bucket_hist(
    const int* __restrict__ rows, int row_off, int* __restrict__ bkt_count,
    int nnz, int NB) {
    __shared__ int cnt[256];
    if (threadIdx.x < NB) cnt[threadIdx.x] = 0;
    __syncthreads();
    for (int e = blockIdx.x * 256 + threadIdx.x; e < nnz; e += gridDim.x * 256)
        atomicAdd(&cnt[(rows[e] + row_off) >> LOG_BR], 1);
    __syncthreads();
    if (threadIdx.x < NB) {
        int c = cnt[threadIdx.x];
        if (c) atomicAdd(&bkt_count[threadIdx.x], c);
    }
}

// S0: single-block exclusive scan of NB (<=256) bucket counts.
__global__ __launch_bounds__(256) void bucket_scan(
    const int* __restrict__ bkt_count, int* __restrict__ bkt_start,
    int* __restrict__ bkt_cursor, int NB, int nnz) {
    __shared__ int s[256];
    int v = (threadIdx.x < NB) ? bkt_count[threadIdx.x] : 0;
    s[threadIdx.x] = v;
    __syncthreads();
    #pragma unroll
    for (int off = 1; off < 256; off <<= 1) {
        int t = (threadIdx.x >= off) ? s[threadIdx.x - off] : 0;
        __syncthreads();
        s[threadIdx.x] += t;
        __syncthreads();
    }
    if (threadIdx.x < NB) {
        int ex = s[threadIdx.x] - v;
        bkt_start[threadIdx.x] = ex;
        bkt_cursor[threadIdx.x] = ex;
    }
    if (threadIdx.x == 0) bkt_start[NB] = nnz;
}

// P1: block-aggregated partition into bucket-major intermediate array.
template <int LOG_BR>
__global__ __launch_bounds__(256) void partition_edges(
    const int* __restrict__ rows, const int* __restrict__ cols,
    const float* __restrict__ vals, int row_off, int col_off,
    int* __restrict__ bkt_cursor, int2* __restrict__ inter, int nnz) {
    __shared__ int cnt[256];
    __shared__ int base[256];
    const int tile = blockIdx.x * 4096;
    cnt[threadIdx.x] = 0;
    __syncthreads();
    int myrow[16];
    #pragma unroll
    for (int i = 0; i < 16; ++i) {
        int e = tile + i * 256 + threadIdx.x;
        int r = (e < nnz) ? (rows[e] + row_off) : -1;
        myrow[i] = r;
        if (r >= 0) atomicAdd(&cnt[r >> LOG_BR], 1);
    }
    __syncthreads();
    {
        int c = cnt[threadIdx.x];
        if (c) base[threadIdx.x] = atomicAdd(&bkt_cursor[threadIdx.x], c);
        cnt[threadIdx.x] = 0;  // reuse as rank counter
    }
    __syncthreads();
    #pragma unroll
    for (int i = 0; i < 16; ++i) {
        int r = myrow[i];
        if (r < 0) continue;
        int b = r >> LOG_BR;
        int rank = atomicAdd(&cnt[b], 1);
        int e = tile + i * 256 + threadIdx.x;
        int rl = r & ((1 << LOG_BR) - 1);
        inter[base[b] + rank] = make_int2((rl << 18) | (cols[e] + col_off),
                                          __float_as_int(vals[e]));
    }
}

// P2: one block per bucket -> rowptr + row-sorted spack. THREADS-wide block
// (1024 for the hot NB=137 path: 4x wave parallelism vs 256).
template <int LOG_BR, int THREADS>
__global__ __launch_bounds__(THREADS) void bucket_to_csr(
    const int* __restrict__ bkt_start, const int2* __restrict__ inter,
    int2* __restrict__ spack, int* __restrict__ rowptr, int n_rows, int nnz) {
    const int BR = 1 << LOG_BR;
    const int C = BR / THREADS;  // rows per thread (>=1 for instantiations used)
    __shared__ int hist[BR];
    __shared__ int bsum[THREADS];
    const int b = blockIdx.x;
    const int lo = bkt_start[b], hi = bkt_start[b + 1];
    #pragma unroll
    for (int j = 0; j < C; ++j) hist[threadIdx.x * C + j] = 0;
    __syncthreads();
    for (int i = lo + threadIdx.x; i < hi; i += THREADS)
        atomicAdd(&hist[inter[i].x >> 18], 1);
    __syncthreads();
    int loc[4];
    int sum = 0;
    #pragma unroll
    for (int j = 0; j < C; ++j) { loc[j] = sum; sum += hist[threadIdx.x * C + j]; }
    bsum[threadIdx.x] = sum;
    __syncthreads();
    #pragma unroll
    for (int off = 1; off < THREADS; off <<= 1) {
        int t = (threadIdx.x >= off) ? bsum[threadIdx.x - off] : 0;
        __syncthreads();
        bsum[threadIdx.x] += t;
        __syncthreads();
    }
    int texcl = bsum[threadIdx.x] - sum;
    __syncthreads();
    #pragma unroll
    for (int j = 0; j < C; ++j) {
        int r = threadIdx.x * C + j;
        int abs0 = lo + texcl + loc[j];
        int grow = (b << LOG_BR) + r;
        if (grow < n_rows) rowptr[grow] = abs0;
        hist[r] = abs0;
    }
    if (b == gridDim.x - 1 && threadIdx.x == 0) rowptr[n_rows] = nnz;
    __syncthreads();
    for (int i = lo + threadIdx.x; i < hi; i += THREADS) {
        int2 p = inter[i];
        int pos = atomicAdd(&hist[p.x >> 18], 1);
        spack[pos] = make_int2(p.x & 0x3FFFF, p.y);
    }
}

// ---------------------------------------------------------------------------
// f32 -> bf16: dst[0..n4A) <- A, dst[n4A..n4tot) <- B  (float4 granularity)
// ---------------------------------------------------------------------------
__global__ __launch_bounds__(256) void concat2_to_bf16(
    const float* __restrict__ A, const float* __restrict__ B, int n4A,
    int n4tot, unsigned short* __restrict__ dst) {
    int gid = blockIdx.x * blockDim.x + threadIdx.x;
    if (gid >= n4tot) return;
    float4 v = (gid < n4A) ? ((const float4*)A)[gid] : ((const float4*)B)[gid - n4A];
    ushort4 o;
    o.x = f2bf(v.x); o.y = f2bf(v.y); o.z = f2bf(v.z); o.w = f2bf(v.w);
    ((ushort4*)dst)[gid] = o;
}

// ---------------------------------------------------------------------------
// Gather SpMM (CSR): 4 rows per wave, 16 lanes per row, 4 dims per lane.
// 4 independent edge streams/wave, unroll-4 each, software-pipelined
// descriptor prefetch. Tail slots gather a hot line and multiply by 0.
// MODE 0: out_bf = bf16(s)
// MODE 1: out_bf = bf16(s); acc = ego0 + s                (ui layer 1)
// MODE 2: out_bf = bf16(s); acc += s                      (ui layer 2)
// MODE 3: acc += s                                        (ui layer 3)
// MODE 4: out_f32 = s; acc = acc*0.25 + s/max(||s||,eps)  (separate ii/uu final)
// MODE 5: same as 4 but block-diagonal cat row->acc row mapping
// Requires n_rows % 16 == 0 (140000/100000/40000 all qualify).
// ---------------------------------------------------------------------------
template <int MODE>
__global__ __launch_bounds__(256) void spmm_csr4(
    const int* __restrict__ rowptr, const int2* __restrict__ spack,
    const unsigned short* __restrict__ x, unsigned short* __restrict__ out_bf,
    float* __restrict__ out_f32, float* __restrict__ acc,
    const float* __restrict__ ego_u, const float* __restrict__ ego_i,
    int n_rows, int nnz) {
    const int wq   = (blockIdx.x * 256 + threadIdx.x) >> 6;  // row quad id
    const int lane = threadIdx.x & 63;
    const int l    = lane & 15;            // lane within row group
    const int row  = wq * 4 + (lane >> 4);

    int j = rowptr[row];
    int e = rowptr[row + 1];
    int rem = e - j;                              // uniform within 16-lane group
    int m1 = max(rem, __shfl_xor(rem, 16, 64));
    int mrem = max(m1, __shfl_xor(m1, 32, 64));   // uniform across wave

    const uint2* __restrict__ xq = (const uint2*)x;  // 4 bf16 per uint2
    const int last = nnz - 1;

    float4 sa[4];
    #pragma unroll
    for (int u = 0; u < 4; ++u) sa[u] = make_float4(0.f, 0.f, 0.f, 0.f);

    if (mrem > 0) {
        int base = j;
        int2 p[4];
        #pragma unroll
        for (int u = 0; u < 4; ++u) p[u] = spack[min(base + u, last)];
        for (;;) {
            uint2 g[4];
            #pragma unroll
            for (int u = 0; u < 4; ++u)
                g[u] = xq[(u < rem) ? ((p[u].x << 4) + l) : l];
            int nb = base + 4;
            int2 q[4];
            #pragma unroll
            for (int u = 0; u < 4; ++u) q[u] = spack[min(nb + u, last)];
            #pragma unroll
            for (int u = 0; u < 4; ++u) {
                float v = (u < rem) ? __int_as_float(p[u].y) : 0.f;
                sa[u].x += v * __uint_as_float(g[u].x << 16);
                sa[u].y += v * __uint_as_float(g[u].x & 0xFFFF0000u);
                sa[u].z += v * __uint_as_float(g[u].y << 16);
                sa[u].w += v * __uint_as_float(g[u].y & 0xFFFF0000u);
            }
            mrem -= 4;
            if (mrem <= 0) break;
            rem -= 4;
            base = nb;
            #pragma unroll
            for (int u = 0; u < 4; ++u) p[u] = q[u];
        }
    }
    float4 s;
    s.x = (sa[0].x + sa[1].x) + (sa[2].x + sa[3].x);
    s.y = (sa[0].y + sa[1].y) + (sa[2].y + sa[3].y);
    s.z = (sa[0].z + sa[1].z) + (sa[2].z + sa[3].z);
    s.w = (sa[0].w + sa[1].w) + (sa[2].w + sa[3].w);

    const size_t idx4 = (size_t)row * 16 + l;  // float4 / ushort4 units
    if (MODE == 0 || MODE == 1 || MODE == 2) {
        ushort4 o;
        o.x = f2bf(s.x); o.y = f2bf(s.y); o.z = f2bf(s.z); o.w = f2bf(s.w);
        ((ushort4*)out_bf)[idx4] = o;
    }
    if (MODE == 1) {
        float4 e4 = (row < N_USERS_C)
            ? ((const float4*)ego_u)[idx4]
            : ((const float4*)ego_i)[(size_t)(row - N_USERS_C) * 16 + l];
        ((float4*)acc)[idx4] = make_float4(e4.x + s.x, e4.y + s.y,
                                           e4.z + s.z, e4.w + s.w);
    } else if (MODE == 2 || MODE == 3) {
        float4 a = ((const float4*)acc)[idx4];
        ((float4*)acc)[idx4] = make_float4(a.x + s.x, a.y + s.y,
                                           a.z + s.z, a.w + s.w);
    } else if (MODE == 4 || MODE == 5) {
        ((float4*)out_f32)[idx4] = s;
        float ss = s.x * s.x + s.y * s.y + s.z * s.z + s.w * s.w;
        #pragma unroll
        for (int off = 1; off < 16; off <<= 1) ss += __shfl_xor(ss, off, 64);
        float inv = 1.f / fmaxf(sqrtf(ss), 1e-12f);
        size_t aidx = idx4;
        if (MODE == 5) {
            int arow = (row < N_ITEMS_C) ? (N_USERS_C + row) : (row - N_ITEMS_C);
            aidx = (size_t)arow * 16 + l;
        }
        float4 a = ((const float4*)acc)[aidx];
        a.x = a.x * 0.25f + s.x * inv;
        a.y = a.y * 0.25f + s.y * inv;
        a.z = a.z * 0.25f + s.z * inv;
        a.w = a.w * 0.25f + s.w * inv;
        ((float4*)acc)[aidx] = a;
    }
}

// ---------------------------------------------------------------------------

template <int MODE>
static inline void run_spmm(const int* rowptr, const int2* spack,
                            const unsigned short* x, unsigned short* out_bf,
                            float* out_f32, float* acc, const float* ego_u,
                            const float* ego_i, int n_rows, int nnz, hipStream_t s) {
    spmm_csr4<MODE><<<n_rows / 16, 256, 0, s>>>(rowptr, spack, x, out_bf, out_f32,
                                                acc, ego_u, ego_i, n_rows, nnz);
}

extern "C" void kernel_launch(void* const* d_in, const int* in_sizes, int n_in,
                              void* d_out, int out_size, void* d_ws, size_t ws_size,
                              hipStream_t stream) {
    const float* user_ui = (const float*)d_in[0];
    const float* item_ui = (const float*)d_in[1];
    const float* uu_emb  = (const float*)d_in[2];
    const float* ii_emb  = (const float*)d_in[3];
    const float* ui_vals = (const float*)d_in[4];
    const float* ii_vals = (const float*)d_in[5];
    const float* uu_vals = (const float*)d_in[6];
    const int* ui_rows = (const int*)d_in[7];
    const int* ui_cols = (const int*)d_in[8];
    const int* ii_rows = (const int*)d_in[9];
    const int* ii_cols = (const int*)d_in[10];
    const int* uu_rows = (const int*)d_in[11];
    const int* uu_cols = (const int*)d_in[12];
    const int nnz_ui = in_sizes[4];
    const int nnz_ii = in_sizes[5];
    const int nnz_uu = in_sizes[6];
    const int nnz_cat = nnz_ii + nnz_uu;

    float* out    = (float*)d_out;
    float* acc    = out;                                  // [140000, 64]
    float* acc_u  = acc;
    float* acc_i  = acc + (size_t)N_USERS_C * DIM_C;
    float* out_ii = out + (size_t)NTOT_C * DIM_C;         // [40000, 64]
    float* out_uu = out_ii + (size_t)N_ITEMS_C * DIM_C;   // [100000, 64]
    float* out_cat = out_ii;  // out_ii then out_uu contiguous -> cat rows 1:1

    const size_t buf_bytes = (size_t)NTOT_C * DIM_C * sizeof(unsigned short);
    const size_t sp_ui  = (size_t)nnz_ui * sizeof(int2);
    const size_t sp_cat = (size_t)nnz_cat * sizeof(int2);
    const size_t meta_bytes = ((size_t)(NTOT_C + 1) + 1024) * sizeof(int);

    // cat layout: [A: spack][B: inter / buf0][C: buf1][meta]
    size_t slotA = sp_cat > sp_ui ? sp_cat : sp_ui;
    size_t slotB = slotA > buf_bytes ? slotA : buf_bytes;
    bool use_cat = ws_size >= slotA + slotB + buf_bytes + meta_bytes;
    if (!use_cat) {  // fallback: separate ii/uu chains
        size_t mx = sp_ui;
        if ((size_t)nnz_ii * sizeof(int2) > mx) mx = (size_t)nnz_ii * sizeof(int2);
        if ((size_t)nnz_uu * sizeof(int2) > mx) mx = (size_t)nnz_uu * sizeof(int2);
        slotA = mx;
        slotB = buf_bytes;  // inter aliases buf0
    }

    char* p = (char*)d_ws;
    int2* spack = (int2*)p;                     p += slotA;
    int2* inter = (int2*)p;
    unsigned short* buf0 = (unsigned short*)p;  p += slotB;
    unsigned short* buf1 = (unsigned short*)p;  p += buf_bytes;
    int* rowptr     = (int*)p;
    int* bkt_count  = rowptr + (NTOT_C + 1);
    int* bkt_start  = bkt_count + 257;
    int* bkt_cursor = bkt_start + 258;

    const int n4tot = NTOT_C * DIM_C / 4;
    const int n4u   = N_USERS_C * DIM_C / 4;
    const int n4i   = N_ITEMS_C * DIM_C / 4;

    // ==== ui chain (3 layers; acc lives in d_out head); BR=1024, NB=137 ====
    {
        const int NB = (NTOT_C + 1023) >> 10;
        hipMemsetAsync(bkt_count, 0, (size_t)NB * sizeof(int), stream);
        bucket_hist<10><<<512, 256, 0, stream>>>(ui_rows, 0, bkt_count, nnz_ui, NB);
        bucket_scan<<<1, 256, 0, stream>>>(bkt_count, bkt_start, bkt_cursor, NB, nnz_ui);
        partition_edges<10><<<(nnz_ui + 4095) / 4096, 256, 0, stream>>>(
            ui_rows, ui_cols, ui_vals, 0, 0, bkt_cursor, inter, nnz_ui);
        bucket_to_csr<10, 1024><<<NB, 1024, 0, stream>>>(bkt_start, inter, spack,
                                                         rowptr, NTOT_C, nnz_ui);
    }
    concat2_to_bf16<<<(n4tot + 255) / 256, 256, 0, stream>>>(user_ui, item_ui,
                                                             n4u, n4tot, buf1);
    run_spmm<1>(rowptr, spack, buf1, buf0, nullptr, acc, user_ui, item_ui,
                NTOT_C, nnz_ui, stream);
    run_spmm<2>(rowptr, spack, buf0, buf1, nullptr, acc, nullptr, nullptr,
                NTOT_C, nnz_ui, stream);
    run_spmm<3>(rowptr, spack, buf1, nullptr, nullptr, acc, nullptr, nullptr,
                NTOT_C, nnz_ui, stream);

    if (use_cat) {
        // ==== fused ii+uu chain: diag(S_ii, S_uu) on [ii_emb; uu_emb] ====
        const int NB = (NTOT_C + 1023) >> 10;
        hipMemsetAsync(bkt_count, 0, (size_t)NB * sizeof(int), stream);
        bucket_hist<10><<<512, 256, 0, stream>>>(ii_rows, 0, bkt_count, nnz_ii, NB);
        bucket_hist<10><<<512, 256, 0, stream>>>(uu_rows, N_ITEMS_C, bkt_count,
                                                 nnz_uu, NB);
        bucket_scan<<<1, 256, 0, stream>>>(bkt_count, bkt_start, bkt_cursor, NB,
                                           nnz_cat);
        partition_edges<10><<<(nnz_ii + 4095) / 4096, 256, 0, stream>>>(
            ii_rows, ii_cols, ii_vals, 0, 0, bkt_cursor, inter, nnz_ii);
        partition_edges<10><<<(nnz_uu + 4095) / 4096, 256, 0, stream>>>(
            uu_rows, uu_cols, uu_vals, N_ITEMS_C, N_ITEMS_C, bkt_cursor, inter,
            nnz_uu);
        bucket_to_csr<10, 1024><<<NB, 1024, 0, stream>>>(bkt_start, inter, spack,
                                                         rowptr, NTOT_C, nnz_cat);
        concat2_to_bf16<<<(n4tot + 255) / 256, 256, 0, stream>>>(ii_emb, uu_emb,
                                                                 n4i, n4tot, buf1);
        run_spmm<0>(rowptr, spack, buf1, buf0, nullptr, nullptr, nullptr, nullptr,
                    NTOT_C, nnz_cat, stream);
        run_spmm<5>(rowptr, spack, buf0, nullptr, out_cat, acc, nullptr, nullptr,
                    NTOT_C, nnz_cat, stream);
    } else {
        // ==== fallback: separate chains ====
        {  // ii: BR=256, NB=157
            const int NB = (N_ITEMS_C + 255) >> 8;
            hipMemsetAsync(bkt_count, 0, (size_t)NB * sizeof(int), stream);
            bucket_hist<8><<<512, 256, 0, stream>>>(ii_rows, 0, bkt_count, nnz_ii, NB);
            bucket_scan<<<1, 256, 0, stream>>>(bkt_count, bkt_start, bkt_cursor,
                                               NB, nnz_ii);
            partition_edges<8><<<(nnz_ii + 4095) / 4096, 256, 0, stream>>>(
                ii_rows, ii_cols, ii_vals, 0, 0, bkt_cursor, inter, nnz_ii);
            bucket_to_csr<8, 256><<<NB, 256, 0, stream>>>(bkt_start, inter, spack,
                                                          rowptr, N_ITEMS_C, nnz_ii);
        }
        concat2_to_bf16<<<(n4i + 255) / 256, 256, 0, stream>>>(ii_emb, ii_emb,
                                                               n4i, n4i, buf0);
        run_spmm<0>(rowptr, spack, buf0, buf1, nullptr, nullptr, nullptr, nullptr,
                    N_ITEMS_C, nnz_ii, stream);
        run_spmm<4>(rowptr, spack, buf1, nullptr, out_ii, acc_i, nullptr, nullptr,
                    N_ITEMS_C, nnz_ii, stream);
        {  // uu: BR=512, NB=196
            const int NB = (N_USERS_C + 511) >> 9;
            hipMemsetAsync(bkt_count, 0, (size_t)NB * sizeof(int), stream);
            bucket_hist<9><<<512, 256, 0, stream>>>(uu_rows, 0, bkt_count, nnz_uu, NB);
            bucket_scan<<<1, 256, 0, stream>>>(bkt_count, bkt_start, bkt_cursor,
                                               NB, nnz_uu);
            partition_edges<9><<<(nnz_uu + 4095) / 4096, 256, 0, stream>>>(
                uu_rows, uu_cols, uu_vals, 0, 0, bkt_cursor, inter, nnz_uu);
            bucket_to_csr<9, 256><<<NB, 256, 0, stream>>>(bkt_start, inter, spack,
                                                          rowptr, N_USERS_C, nnz_uu);
        }
        concat2_to_bf16<<<(n4u + 255) / 256, 256, 0, stream>>>(uu_emb, uu_emb,
                                                               n4u, n4u, buf0);
        run_spmm<0>(rowptr, spack, buf0, buf1, nullptr, nullptr, nullptr, nullptr,
                    N_USERS_C, nnz_uu, stream);
        run_spmm<4>(rowptr, spack, buf1, nullptr, out_uu, acc_u, nullptr, nullptr,
                    N_USERS_C, nnz_uu, stream);
    }
}